// Round 12
// baseline (205.429 us; speedup 1.0000x reference)
//
#include <hip/hip_runtime.h>
#include <math.h>

#define NODES 50000
#define EDGES 800000
#define FIN   256
#define HD    64      // H*D = 4*16
#define NEG   0.2f

#define NB          196          // dst buckets (dst>>8), ceil(50000/256)
#define STAGE_BLOCKS 196         // 4096 edges per block
#define PREP_BLOCKS 128          // 32768/256
#define PROJ_BLOCKS2 1564        // 782 row-tiles x 2 column-halves

typedef __attribute__((ext_vector_type(8))) short bf16x8;
typedef __attribute__((ext_vector_type(4))) float f32x4;

// ---------------------------------------------------------------------------
// Split fp32 -> hi/lo bf16 (truncation split; exact residual).
// ---------------------------------------------------------------------------
__device__ __forceinline__ unsigned pack_hi(unsigned a, unsigned b)
{ return (a >> 16) | (b & 0xFFFF0000u); }

__device__ __forceinline__ void split8(const float4 x01, const float4 x23,
                                       bf16x8& hi, bf16x8& lo)
{
    const float xs[8] = { x01.x, x01.y, x01.z, x01.w, x23.x, x23.y, x23.z, x23.w };
    union { unsigned w[4]; bf16x8 v; } H, L;
#pragma unroll
    for (int p = 0; p < 4; ++p) {
        const float a = xs[2 * p], b = xs[2 * p + 1];
        const unsigned ba = __float_as_uint(a), bb = __float_as_uint(b);
        H.w[p] = pack_hi(ba, bb);
        const float la = a - __uint_as_float(ba & 0xFFFF0000u);
        const float lb = b - __uint_as_float(bb & 0xFFFF0000u);
        L.w[p] = pack_hi(__float_as_uint(la), __float_as_uint(lb));
    }
    hi = H.v; lo = L.v;
}

// ---------------------------------------------------------------------------
// Fused: prep_b (blocks 0..127) || bucket-count (128..323).
// ---------------------------------------------------------------------------
__global__ void prep_count_kernel(const float* __restrict__ Wsrc,
                                  const float* __restrict__ Wdst,
                                  short* __restrict__ Bhi, short* __restrict__ Blo,
                                  const int* __restrict__ dst, int* __restrict__ bcnt)
{
    const int b = blockIdx.x;
    const int t = threadIdx.x;
    if (b < PREP_BLOCKS) {
        const int i = b * 256 + t;                      // 0..32767
        const int row = i >> 8, k = i & 255;
        const float x = (row < 64) ? Wsrc[row * FIN + k] : Wdst[(row - 64) * FIN + k];
        const unsigned bb = __float_as_uint(x);
        const float l = x - __uint_as_float(bb & 0xFFFF0000u);
        Bhi[i] = (short)(bb >> 16);
        Blo[i] = (short)(__float_as_uint(l) >> 16);
        return;
    }
    __shared__ int sH[NB];
    for (int i = t; i < NB; i += 256) sH[i] = 0;
    __syncthreads();
    const int e0 = (b - PREP_BLOCKS) * 4096;
#pragma unroll
    for (int k = 0; k < 16; ++k) {
        const int e = e0 + k * 256 + t;
        if (e < EDGES) atomicAdd(&sH[dst[e] >> 8], 1);
    }
    __syncthreads();
    for (int i = t; i < NB; i += 256) {
        const int c = sH[i];
        if (c) atomicAdd(&bcnt[i], c);
    }
}

// ---------------------------------------------------------------------------
// Bucket scan (1 block): bbase = exclusive scan of bcnt; seeds bcur;
// writes offs[NODES]=EDGES.
// ---------------------------------------------------------------------------
__global__ void bscan_kernel(const int* __restrict__ bcnt, int* __restrict__ bbase,
                             int* __restrict__ bcur, int* __restrict__ offs)
{
    __shared__ int s[256];
    const int t = threadIdx.x;
    const int v = (t < NB) ? bcnt[t] : 0;
    s[t] = v;
    __syncthreads();
    for (int off = 1; off < 256; off <<= 1) {
        const int x = (t >= off) ? s[t - off] : 0;
        __syncthreads();
        s[t] += x;
        __syncthreads();
    }
    const int excl = s[t] - v;
    if (t <= NB) bbase[t] = excl;      // t==NB -> total == EDGES
    if (t < NB)  bcur[t]  = excl;
    if (t == 0)  offs[NODES] = EDGES;
}

// ---------------------------------------------------------------------------
// Fused: MFMA projection (blocks 0..1563) || bucket-stage (1564..1759).
//
// proj: block = one 64-row tile x one 64-col half (half 0 -> fs/Wsrc,
// half 1 -> fd/Wdst). The ENTIRE B-half (hi+lo, all K) is preloaded into
// LDS once (64 KB), then ONE barrier, then each wave computes its
// 16 rows x 64 cols over all 8 K-slices with NO further barriers — the
// A register ring (depth 2) stays in flight (no vmcnt(0) barrier drains,
// the R6-R11 latency killer). 3-term split-bf16 MFMA.
// ---------------------------------------------------------------------------
__global__ __launch_bounds__(256) void proj_stage_kernel(
    const float* __restrict__ feat,
    const short* __restrict__ Bhi, const short* __restrict__ Blo,
    const float* __restrict__ bsrc, const float* __restrict__ bdst,
    float* __restrict__ fs, float* __restrict__ fd,
    const int* __restrict__ src, const int* __restrict__ dst,
    int* __restrict__ bcur, unsigned* __restrict__ bedge)
{
    __shared__ short sB[2][2048 * 8];              // [plane][unit*8] 64 KB
    __shared__ int   sH[NB], sBase[NB];            // stage-pass bins

    const int t = threadIdx.x;

    if (blockIdx.x >= PROJ_BLOCKS2) {
        // ---------------- bucket-stage ----------------
        const int e0 = (blockIdx.x - PROJ_BLOCKS2) * 4096;
        for (int i = t; i < NB; i += 256) sH[i] = 0;
        __syncthreads();
#pragma unroll
        for (int k = 0; k < 16; ++k) {
            const int e = e0 + k * 256 + t;
            if (e < EDGES) atomicAdd(&sH[dst[e] >> 8], 1);
        }
        __syncthreads();
        for (int i = t; i < NB; i += 256) {
            const int c = sH[i];
            sBase[i] = c ? atomicAdd(&bcur[i], c) : 0;
            sH[i] = 0;
        }
        __syncthreads();
#pragma unroll
        for (int k = 0; k < 16; ++k) {
            const int e = e0 + k * 256 + t;
            if (e < EDGES) {
                const int d = dst[e];
                const int b = d >> 8;
                const int p = sBase[b] + atomicAdd(&sH[b], 1);
                bedge[p] = (unsigned)src[e] | ((unsigned)(d & 255) << 16);
            }
        }
        return;
    }

    // ---------------- proj ----------------
    const int half = blockIdx.x & 1;               // 0 -> fs, 1 -> fd
    const int tile = blockIdx.x >> 1;
    const int lane = t & 63;
    const int w    = t >> 6;                       // wave 0..3
    const int fr   = lane & 15;
    const int fq   = lane >> 4;                    // k-octet 0..3

    const short* Bh = Bhi + (size_t)half * 64 * FIN;
    const short* Bl = Blo + (size_t)half * 64 * FIN;

    const int r0 = tile * 64 + w * 16;             // wave's first row
    int rowA = r0 + fr;  if (rowA >= NODES) rowA = NODES - 1;
    const float* pA = feat + (size_t)rowA * FIN + fq * 8;

    // issue first two A slices before LDS staging (overlap; drained once at bar)
    float4 aR[3][2];
    aR[0][0] = *(const float4*)(pA);       aR[0][1] = *(const float4*)(pA + 4);
    aR[1][0] = *(const float4*)(pA + 32);  aR[1][1] = *(const float4*)(pA + 36);

    // stage entire B-half (hi+lo, all K) into LDS: unit u -> (s,fq,c)
#pragma unroll
    for (int j = 0; j < 8; ++j) {
        const int u   = t + j * 256;               // 0..2047
        const int s   = u >> 8;                    // k-slice
        const int fqq = (u >> 6) & 3;              // k-octet
        const int c   = u & 63;                    // col within half
        const size_t go = (size_t)c * FIN + s * 32 + fqq * 8;
        *(float4*)&sB[0][(size_t)u * 8] = *(const float4*)(Bh + go);
        *(float4*)&sB[1][(size_t)u * 8] = *(const float4*)(Bl + go);
    }
    __syncthreads();                               // the ONLY barrier

    f32x4 acc[4];
#pragma unroll
    for (int n = 0; n < 4; ++n) acc[n] = (f32x4){0.f, 0.f, 0.f, 0.f};

#pragma unroll
    for (int ks = 0; ks < 8; ++ks) {
        if (ks < 6) {                              // A two slices ahead (ring)
            aR[(ks + 2) % 3][0] = *(const float4*)(pA + (ks + 2) * 32);
            aR[(ks + 2) % 3][1] = *(const float4*)(pA + (ks + 2) * 32 + 4);
        }
        bf16x8 ah, al;
        split8(aR[ks % 3][0], aR[ks % 3][1], ah, al);
#pragma unroll
        for (int nf = 0; nf < 4; ++nf) {
            const int u = (ks * 4 + fq) * 64 + nf * 16 + fr;
            const bf16x8 bh = *(const bf16x8*)&sB[0][(size_t)u * 8];
            const bf16x8 bl = *(const bf16x8*)&sB[1][(size_t)u * 8];
            acc[nf] = __builtin_amdgcn_mfma_f32_16x16x32_bf16(ah, bh, acc[nf], 0, 0, 0);
            acc[nf] = __builtin_amdgcn_mfma_f32_16x16x32_bf16(al, bh, acc[nf], 0, 0, 0);
            acc[nf] = __builtin_amdgcn_mfma_f32_16x16x32_bf16(ah, bl, acc[nf], 0, 0, 0);
        }
    }

    // epilogue: bias + store.  D: row = fq*4+r, col = fr (m89/m91 mapping)
    const float* bias = half ? bdst : bsrc;
    float* outp = half ? fd : fs;
#pragma unroll
    for (int nf = 0; nf < 4; ++nf) {
        const int c = nf * 16 + fr;
        const float bv = bias[c];
#pragma unroll
        for (int r = 0; r < 4; ++r) {
            const int row = r0 + fq * 4 + r;
            if (row < NODES)
                outp[(size_t)row * HD + c] = acc[nf][r] + bv;
        }
    }
}

// ---------------------------------------------------------------------------
// Bucket scatter: one block per bucket. Derives per-node degrees from the
// bucket's packed edges (LDS counters), LDS-scans into offs[], then places
// edges into csr — all traffic confined to the bucket's region.
// ---------------------------------------------------------------------------
__global__ __launch_bounds__(256) void bucket_scatter_kernel(
    const int* __restrict__ bbase, const unsigned* __restrict__ bedge,
    int* __restrict__ offs, unsigned short* __restrict__ csr)
{
    __shared__ int s[256];
    __shared__ int pl[256];
    const int b = blockIdx.x;                      // 0..195
    const int t = threadIdx.x;
    const int start = bbase[b];                    // block-uniform
    const int end   = bbase[b + 1];

    s[t] = 0;
    __syncthreads();
    for (int i = start + t; i < end; i += 256)
        atomicAdd(&s[(bedge[i] >> 16) & 255], 1);
    __syncthreads();

    const int v = s[t];
    __syncthreads();
    for (int off = 1; off < 256; off <<= 1) {
        const int x = (t >= off) ? s[t - off] : 0;
        __syncthreads();
        s[t] += x;
        __syncthreads();
    }
    const int excl = s[t] - v;

    const int node = b * 256 + t;
    if (node < NODES) offs[node] = start + excl;
    pl[t] = excl;
    __syncthreads();

    for (int i = start + t; i < end; i += 256) {
        const unsigned pk = bedge[i];
        const int rel = atomicAdd(&pl[(pk >> 16) & 255], 1);
        csr[start + rel] = (unsigned short)(pk & 0xFFFFu);
    }
}

// ---------------------------------------------------------------------------
// Per-destination-node GAT: one wave per node, lane = h*16+d.
// No max-subtraction (scores bounded; exp(s)/sum exp(s) identical math).
// Head reduce via DPP (VALU), edge broadcast via readlane, 4-edge unroll.
// ---------------------------------------------------------------------------
__device__ __forceinline__ float head_sum16(float x)
{
    x += __int_as_float(__builtin_amdgcn_update_dpp(0, __float_as_int(x), 0xB1,  0xf, 0xf, true)); // ^1
    x += __int_as_float(__builtin_amdgcn_update_dpp(0, __float_as_int(x), 0x4E,  0xf, 0xf, true)); // ^2
    x += __int_as_float(__builtin_amdgcn_update_dpp(0, __float_as_int(x), 0x141, 0xf, 0xf, true)); // half-mirror
    x += __int_as_float(__builtin_amdgcn_update_dpp(0, __float_as_int(x), 0x140, 0xf, 0xf, true)); // mirror
    return x;
}

__global__ __launch_bounds__(256) void gat_kernel(
    const float* __restrict__ fs, const float* __restrict__ fd,
    const float* __restrict__ attn,
    const int* __restrict__ offs, const unsigned short* __restrict__ csr,
    float* __restrict__ out)
{
    const int wid  = (blockIdx.x * blockDim.x + threadIdx.x) >> 6;  // node id
    const int lane = threadIdx.x & 63;
    if (wid >= NODES) return;

    const float er = fd[(size_t)wid * HD + lane];
    const float aw = attn[lane];
    const int start = __builtin_amdgcn_readfirstlane(offs[wid]);
    const int end   = __builtin_amdgcn_readfirstlane(offs[wid + 1]);

    float s = 0.f, acc = 0.f;

    for (int base = start; base < end; base += 64) {
        const int rem = end - base;
        const int cnt = rem < 64 ? rem : 64;
        int srcv = 0;
        if (lane < cnt) srcv = (int)csr[base + lane];

        int j = 0;
        for (; j + 4 <= cnt; j += 4) {
            const int i0 = __builtin_amdgcn_readlane(srcv, j + 0);
            const int i1 = __builtin_amdgcn_readlane(srcv, j + 1);
            const int i2 = __builtin_amdgcn_readlane(srcv, j + 2);
            const int i3 = __builtin_amdgcn_readlane(srcv, j + 3);
            const float el0 = fs[(size_t)i0 * HD + lane];
            const float el1 = fs[(size_t)i1 * HD + lane];
            const float el2 = fs[(size_t)i2 * HD + lane];
            const float el3 = fs[(size_t)i3 * HD + lane];
            const float t0 = el0 + er, t1 = el1 + er, t2 = el2 + er, t3 = el3 + er;
            const float e0 = fmaf(NEG, fminf(t0, 0.f), fmaxf(t0, 0.f));
            const float e1 = fmaf(NEG, fminf(t1, 0.f), fmaxf(t1, 0.f));
            const float e2 = fmaf(NEG, fminf(t2, 0.f), fmaxf(t2, 0.f));
            const float e3 = fmaf(NEG, fminf(t3, 0.f), fmaxf(t3, 0.f));
            const float p0 = head_sum16(e0 * aw);
            const float p1 = head_sum16(e1 * aw);
            const float p2 = head_sum16(e2 * aw);
            const float p3 = head_sum16(e3 * aw);
            const float pe0 = __expf(p0);
            const float pe1 = __expf(p1);
            const float pe2 = __expf(p2);
            const float pe3 = __expf(p3);
            s += (pe0 + pe1) + (pe2 + pe3);
            acc = fmaf(pe0, el0, fmaf(pe1, el1, fmaf(pe2, el2, fmaf(pe3, el3, acc))));
        }
        for (; j < cnt; ++j) {
            const int i0 = __builtin_amdgcn_readlane(srcv, j);
            const float el0 = fs[(size_t)i0 * HD + lane];
            const float t0 = el0 + er;
            const float e0 = fmaf(NEG, fminf(t0, 0.f), fmaxf(t0, 0.f));
            const float pe0 = __expf(head_sum16(e0 * aw));
            s += pe0;
            acc = fmaf(pe0, el0, acc);
        }
    }
    out[(size_t)wid * HD + lane] = (end > start) ? (acc / s) : 0.f;
}

// ---------------------------------------------------------------------------
extern "C" void kernel_launch(void* const* d_in, const int* in_sizes, int n_in,
                              void* d_out, int out_size, void* d_ws, size_t ws_size,
                              hipStream_t stream)
{
    const float* feat = (const float*)d_in[0];
    const int*   src  = (const int*)  d_in[1];
    const int*   dst  = (const int*)  d_in[2];
    const float* Wsrc = (const float*)d_in[3];
    const float* bsrc = (const float*)d_in[4];
    const float* Wdst = (const float*)d_in[5];
    const float* bdst = (const float*)d_in[6];
    const float* attn = (const float*)d_in[7];
    float* out = (float*)d_out;

    // workspace layout (~31 MB)
    float* fs     = (float*)d_ws;                    // N*64 f32
    float* fd     = fs + (size_t)NODES * HD;         // N*64 f32
    int*   offs   = (int*)(fd + (size_t)NODES * HD); // N+1 (+pad)
    int*   bcnt   = offs + (NODES + 16);             // 256
    int*   bbase  = bcnt + 256;                      // 256 (197 used)
    int*   bcur   = bbase + 256;                     // 256
    unsigned* bedge = (unsigned*)(bcur + 256);       // E packed (src|dlow<<16)
    unsigned short* csr = (unsigned short*)(bedge + EDGES); // E ushort
    short* Bhi    = (short*)(csr + EDGES);           // 128*256 bf16
    short* Blo    = Bhi + 128 * FIN;                 // 128*256 bf16

    hipMemsetAsync(bcnt, 0, 256 * sizeof(int), stream);

    prep_count_kernel<<<PREP_BLOCKS + STAGE_BLOCKS, 256, 0, stream>>>(
        Wsrc, Wdst, Bhi, Blo, dst, bcnt);
    bscan_kernel<<<1, 256, 0, stream>>>(bcnt, bbase, bcur, offs);
    proj_stage_kernel<<<PROJ_BLOCKS2 + STAGE_BLOCKS, 256, 0, stream>>>(
        feat, Bhi, Blo, bsrc, bdst, fs, fd, src, dst, bcur, bedge);
    bucket_scatter_kernel<<<NB, 256, 0, stream>>>(bbase, bedge, offs, csr);
    gat_kernel<<<((size_t)NODES * 64 + 255) / 256, 256, 0, stream>>>(
        fs, fd, attn, offs, csr, out);
}